// Round 7
// baseline (345.735 us; speedup 1.0000x reference)
//
#include <hip/hip_runtime.h>
#include <math.h>

// Qwen3Attention: T=2048, HID=2048, H=16, KV=8, D=128
#define T_TOK 2048
#define HID 2048
#define NH 16
#define NKV 8
#define HD 128
#define QKV_N 4096
#define EPS 1e-6f

typedef unsigned short u16;
typedef unsigned int   u32;
typedef __attribute__((ext_vector_type(8))) u16   u16x8;
typedef __attribute__((ext_vector_type(8))) short short8;
typedef __attribute__((ext_vector_type(4))) float floatx4;
typedef __attribute__((ext_vector_type(4))) u32   u32x4;

__device__ __forceinline__ u16 f2bf(float x) {           // RNE f32->bf16
    u32 u = __float_as_uint(x);
    u = (u + 0x7fffu + ((u >> 16) & 1u)) >> 16;
    return (u16)u;
}
__device__ __forceinline__ float bf2f(u16 h) {
    return __uint_as_float(((u32)h) << 16);
}

// ---------------------------------------------------------------------------
// f32 -> bf16 elementwise (8 elems/thread). n must be a multiple of 2048.
// ---------------------------------------------------------------------------
__global__ __launch_bounds__(256) void cvt_f32_bf16(
    const float* __restrict__ in, u16* __restrict__ out)
{
    const size_t i = ((size_t)blockIdx.x * 256 + threadIdx.x) * 8;
    float4 a = *(const float4*)(in + i);
    float4 b = *(const float4*)(in + i + 4);
    u16x8 o;
    o[0] = f2bf(a.x); o[1] = f2bf(a.y); o[2] = f2bf(a.z); o[3] = f2bf(a.w);
    o[4] = f2bf(b.x); o[5] = f2bf(b.y); o[6] = f2bf(b.z); o[7] = f2bf(b.w);
    *(u16x8*)(out + i) = o;
}

// ---------------------------------------------------------------------------
// bf16 MFMA GEMM (m97 pattern): C[M,N] = A[M,K]*B[N,K]^T
// 128x128 tile, BK=32, 256 thr; global_load_lds width=16 staging.
// ---------------------------------------------------------------------------
template<bool OUT_BF16>
__global__ __launch_bounds__(256) void gemm_bt_bf16(
    const u16* __restrict__ A, const u16* __restrict__ B,
    void* __restrict__ Cv, int K, int lda, int ldb, int ldc)
{
    __shared__ short As[128 * 32];
    __shared__ short Bs[128 * 32];

    const int tid = threadIdx.x;
    const int w   = tid >> 6;
    const int l   = tid & 63;
    const int m0  = blockIdx.y * 128;
    const int n0  = blockIdx.x * 128;
    const int wm  = (w >> 1) * 64;
    const int wn  = (w & 1) * 64;
    const int lm  = l & 15;
    const int ko8 = (l >> 4) * 8;

    const u16* gA0 = A + (size_t)(m0      + (tid >> 2)) * lda + (tid & 3) * 8;
    const u16* gA1 = A + (size_t)(m0 + 64 + (tid >> 2)) * lda + (tid & 3) * 8;
    const u16* gB0 = B + (size_t)(n0      + (tid >> 2)) * ldb + (tid & 3) * 8;
    const u16* gB1 = B + (size_t)(n0 + 64 + (tid >> 2)) * ldb + (tid & 3) * 8;
    short* lA0 = As + w * 512;
    short* lA1 = As + 2048 + w * 512;
    short* lB0 = Bs + w * 512;
    short* lB1 = Bs + 2048 + w * 512;

    floatx4 acc[4][4];
    #pragma unroll
    for (int i = 0; i < 4; ++i)
        #pragma unroll
        for (int j = 0; j < 4; ++j) acc[i][j] = (floatx4){0.f, 0.f, 0.f, 0.f};

    for (int k0 = 0; k0 < K; k0 += 32) {
        __syncthreads();
        __builtin_amdgcn_global_load_lds(
            (const __attribute__((address_space(1))) u32*)(gA0 + k0),
            (__attribute__((address_space(3))) u32*)lA0, 16, 0, 0);
        __builtin_amdgcn_global_load_lds(
            (const __attribute__((address_space(1))) u32*)(gA1 + k0),
            (__attribute__((address_space(3))) u32*)lA1, 16, 0, 0);
        __builtin_amdgcn_global_load_lds(
            (const __attribute__((address_space(1))) u32*)(gB0 + k0),
            (__attribute__((address_space(3))) u32*)lB0, 16, 0, 0);
        __builtin_amdgcn_global_load_lds(
            (const __attribute__((address_space(1))) u32*)(gB1 + k0),
            (__attribute__((address_space(3))) u32*)lB1, 16, 0, 0);
        __syncthreads();

        short8 af[4], bfr[4];
        #pragma unroll
        for (int i = 0; i < 4; ++i)
            af[i] = *(const short8*)(As + (wm + i * 16 + lm) * 32 + ko8);
        #pragma unroll
        for (int j = 0; j < 4; ++j)
            bfr[j] = *(const short8*)(Bs + (wn + j * 16 + lm) * 32 + ko8);
        #pragma unroll
        for (int i = 0; i < 4; ++i)
            #pragma unroll
            for (int j = 0; j < 4; ++j)
                acc[i][j] = __builtin_amdgcn_mfma_f32_16x16x32_bf16(
                    af[i], bfr[j], acc[i][j], 0, 0, 0);
    }

    const int r0 = (l >> 4) * 4;
    #pragma unroll
    for (int i = 0; i < 4; ++i)
        #pragma unroll
        for (int j = 0; j < 4; ++j)
            #pragma unroll
            for (int r = 0; r < 4; ++r) {
                const int row = m0 + wm + i * 16 + r0 + r;
                const int col = n0 + wn + j * 16 + lm;
                if (OUT_BF16)
                    ((u16*)Cv)[(size_t)row * ldc + col] = f2bf(acc[i][j][r]);
                else
                    ((float*)Cv)[(size_t)row * ldc + col] = acc[i][j][r];
            }
}

// ---------------------------------------------------------------------------
// RMSNorm + RoPE, in-place on bf16 qkv. grid=(T, NH+NKV), 128 thr.
// ---------------------------------------------------------------------------
__global__ __launch_bounds__(128) void norm_rope(
    u16* __restrict__ qkv, const int* __restrict__ positions,
    const float* __restrict__ qw, const float* __restrict__ kw)
{
    const int t   = blockIdx.x;
    const int hh  = blockIdx.y;
    const int tid = threadIdx.x;

    u16* p; const float* w;
    if (hh < NH) { p = qkv + (size_t)t*QKV_N + hh*HD;              w = qw; }
    else         { p = qkv + (size_t)t*QKV_N + NH*HD + (hh-NH)*HD; w = kw; }

    float x = bf2f(p[tid]);

    __shared__ float red[2];
    float ss = x * x;
    #pragma unroll
    for (int o = 32; o > 0; o >>= 1) ss += __shfl_down(ss, o);
    if ((tid & 63) == 0) red[tid >> 6] = ss;
    __syncthreads();
    const float var = (red[0] + red[1]) * (1.0f / (float)HD);
    float xn = x * rsqrtf(var + EPS) * w[tid];

    __shared__ float sx[HD];
    sx[tid] = xn;
    __syncthreads();

    const int   pos = positions[t];
    const int   i   = tid & 63;
    const float inv_freq = exp2f(-(float)i * 0.311430758895690f); // log2(1e6)/64
    const float ang = (float)pos * inv_freq;
    const float s = sinf(ang);   // NOTE: sincosf ptr order trap (r1/r2 bug)
    const float c = cosf(ang);

    float out;
    if (tid < 64) out = sx[i]      * c - sx[i + 64] * s;
    else          out = sx[i + 64] * c + sx[i]      * s;
    p[tid] = f2bf(out);
}

// ---------------------------------------------------------------------------
// V transpose: vt[kv][d][t] = qkv[t][3072 + kv*128 + d]. 32x32 LDS tiles.
// ---------------------------------------------------------------------------
__global__ __launch_bounds__(256) void v_transpose(
    const u16* __restrict__ qkv, u16* __restrict__ vt)
{
    const int kv = blockIdx.z;
    const int d0 = blockIdx.y * 32;
    const int t0 = blockIdx.x * 32;
    const int tid = threadIdx.x;
    __shared__ u16 tile[32][33];
    const int r  = tid >> 5;   // 0..7
    const int cc = tid & 31;
    #pragma unroll
    for (int p = 0; p < 4; ++p)
        tile[r + p*8][cc] =
            qkv[(size_t)(t0 + r + p*8)*QKV_N + (NH*HD + NKV*HD) + kv*HD + d0 + cc];
    __syncthreads();
    #pragma unroll
    for (int p = 0; p < 4; ++p)
        vt[(size_t)kv*HD*T_TOK + (size_t)(d0 + r + p*8)*T_TOK + t0 + cc] =
            tile[cc][r + p*8];
}

// ---------------------------------------------------------------------------
// Split-s MFMA flash attention. grid = (T/64, NH, 2); 256 thr = 4 waves.
// blockIdx.z selects a contiguous half of the k-tile range; each block emits
// an UNNORMALIZED partial (O bf16, m/l f32) for its 64 queries. Q fragments
// live in registers (wave w owns queries 16w..16w+15). S^T = K·Q^T puts the
// query index at C/D col=lane&15 -> per-lane softmax stats. P goes C/D->A
// layout via register shuffles (lane&15-preserving). Vt pre-transposed.
// ---------------------------------------------------------------------------
__global__ __launch_bounds__(256) void attn_mfma(
    const u16* __restrict__ qkv, const u16* __restrict__ vt,
    u16* __restrict__ Opart, float2* __restrict__ ml)
{
    const int qt   = (int)(gridDim.x - 1) - (int)blockIdx.x;  // heavy first
    const int h    = blockIdx.y;
    const int half = blockIdx.z;
    const int kvh  = h >> 1;
    const int t0   = qt * 64;
    const int tid  = threadIdx.x;
    const int w    = tid >> 6;
    const int l    = tid & 63;
    const int q4   = l >> 4;       // quad group 0..3
    const int c    = l & 15;       // col (query) index within 16

    __shared__ short Ks[64 * 136];   // 17408 B (pad 136 -> 2-way banks, free)
    __shared__ short Vts[128 * 72];  // 18432 B -> 35840 B total (4 blk/CU)

    // ---- Q fragments in registers: bq[kk] = Q[w*16+c][kk*32+q4*8 ..+8] ----
    short8 bq[4];
    {
        const u16* qrow = qkv + (size_t)(t0 + w*16 + c) * QKV_N + h*HD;
        #pragma unroll
        for (int kk = 0; kk < 4; ++kk)
            bq[kk] = *(const short8*)(qrow + kk*32 + q4*8);
    }

    float m_run = -3.0e38f, l_run = 0.f;
    floatx4 accO[8];
    #pragma unroll
    for (int db = 0; db < 8; ++db) accO[db] = (floatx4){0.f, 0.f, 0.f, 0.f};

    const u16* kg = qkv + NH*HD + (size_t)kvh*HD;
    const u16* vg = vt + (size_t)kvh * HD * T_TOK;

    const float Cs = 0.12751744f;   // (1/sqrt(128)) * log2(e)

    const int nt  = qt + 1;
    const int nh0 = (nt + 1) >> 1;          // half0 gets ceil, half1 diagonal
    const int tlo = half ? nh0 : 0;
    const int thi = half ? nt  : nh0;

    for (int tile = tlo; tile < thi; ++tile) {
        const int s0 = tile * 64;

        __syncthreads();   // prev iteration's K/Vt reads complete
        {   // stage K tile: rows s0..s0+63
            const int r = tid >> 2, c0 = (tid & 3) * 32;
            const u16* g = kg + (size_t)(s0 + r)*QKV_N + c0;
            #pragma unroll
            for (int p = 0; p < 4; ++p)
                *(u16x8*)(Ks + r*136 + c0 + p*8) = *(const u16x8*)(g + p*8);
        }
        {   // stage Vt tile: rows d=0..127, cols s0..s0+63
            const int d = tid >> 1, c0 = (tid & 1) * 32;
            const u16* g = vg + (size_t)d * T_TOK + s0 + c0;
            #pragma unroll
            for (int p = 0; p < 4; ++p)
                *(u16x8*)(Vts + d*72 + c0 + p*8) = *(const u16x8*)(g + p*8);
        }
        __syncthreads();

        // ---- S^T = K Q^T : accS[sb] = s rows [16sb,16sb+16), q col 16w+c ----
        floatx4 accS[4];
        #pragma unroll
        for (int sb = 0; sb < 4; ++sb) accS[sb] = (floatx4){0.f, 0.f, 0.f, 0.f};
        #pragma unroll
        for (int kk = 0; kk < 4; ++kk) {
            #pragma unroll
            for (int sb = 0; sb < 4; ++sb) {
                short8 ak = *(const short8*)(Ks + (sb*16 + c)*136 + kk*32 + q4*8);
                accS[sb] = __builtin_amdgcn_mfma_f32_16x16x32_bf16(ak, bq[kk], accS[sb], 0, 0, 0);
            }
        }

        // ---- causal mask on the diagonal tile (s0 == t0 there) ----
        if (tile == qt) {
            #pragma unroll
            for (int sb = 0; sb < 4; ++sb)
                #pragma unroll
                for (int r = 0; r < 4; ++r) {
                    const int s_loc = sb*16 + q4*4 + r;
                    const int t_loc = w*16 + c;
                    if (s_loc > t_loc) accS[sb][r] = -1.0e30f;
                }
        }

        // ---- online softmax (per query col c) ----
        float mt = -3.0e38f;
        #pragma unroll
        for (int sb = 0; sb < 4; ++sb)
            #pragma unroll
            for (int r = 0; r < 4; ++r) mt = fmaxf(mt, accS[sb][r]);
        mt = fmaxf(mt, __shfl_xor(mt, 16));
        mt = fmaxf(mt, __shfl_xor(mt, 32));

        const float m_new = fmaxf(m_run, mt);
        const float alpha = exp2f((m_run - m_new) * Cs);  // 0 on first tile
        m_run = m_new;

        float P[4][4];
        float lsum = 0.f;
        #pragma unroll
        for (int sb = 0; sb < 4; ++sb)
            #pragma unroll
            for (int r = 0; r < 4; ++r) {
                const float e = exp2f((accS[sb][r] - m_new) * Cs);
                P[sb][r] = e;
                lsum += e;
            }
        lsum += __shfl_xor(lsum, 16);
        lsum += __shfl_xor(lsum, 32);
        l_run = l_run * alpha + lsum;

        // ---- rescale O by alpha (alpha per col c; O rows are 4q+r) ----
        #pragma unroll
        for (int r = 0; r < 4; ++r) {
            const float ar = __shfl(alpha, (l & 48) | (q4*4 + r));
            #pragma unroll
            for (int db = 0; db < 8; ++db) accO[db][r] *= ar;
        }

        // ---- pack P to bf16 pairs ----
        u32 Pp[4][2];
        #pragma unroll
        for (int sb = 0; sb < 4; ++sb)
            #pragma unroll
            for (int p = 0; p < 2; ++p)
                Pp[sb][p] = (u32)f2bf(P[sb][2*p]) | ((u32)f2bf(P[sb][2*p+1]) << 16);

        // ---- PV: O[m][d] += P[m][s] * Vt[d][s] ----
        const int src0 = ((2*q4    ) & 3) * 16 + c;
        const int src1 = ((2*q4 + 1) & 3) * 16 + c;
        const bool hiq = q4 >= 2;
        #pragma unroll
        for (int k2 = 0; k2 < 2; ++k2) {
            u32 x0 = __shfl(Pp[2*k2][0],   src0), y0 = __shfl(Pp[2*k2+1][0], src0);
            u32 x1 = __shfl(Pp[2*k2][1],   src0), y1 = __shfl(Pp[2*k2+1][1], src0);
            u32 x2 = __shfl(Pp[2*k2][0],   src1), y2 = __shfl(Pp[2*k2+1][0], src1);
            u32 x3 = __shfl(Pp[2*k2][1],   src1), y3 = __shfl(Pp[2*k2+1][1], src1);
            u32x4 av;
            av.x = hiq ? y0 : x0;  av.y = hiq ? y1 : x1;
            av.z = hiq ? y2 : x2;  av.w = hiq ? y3 : x3;
            const short8 aP = __builtin_bit_cast(short8, av);
            #pragma unroll
            for (int db = 0; db < 8; ++db) {
                short8 bv = *(const short8*)(Vts + (db*16 + c)*72 + k2*32 + q4*8);
                accO[db] = __builtin_amdgcn_mfma_f32_16x16x32_bf16(aP, bv, accO[db], 0, 0, 0);
            }
        }
    }

    // ---- write UNNORMALIZED partial + (m,l) per query row ----
    const size_t pbase = (size_t)(half * NH + h) * T_TOK;
    #pragma unroll
    for (int r = 0; r < 4; ++r) {
        const int qloc = q4*4 + r;
        const float mr = __shfl(m_run, (l & 48) | qloc);
        const float lr = __shfl(l_run, (l & 48) | qloc);
        const int row_g = t0 + w*16 + qloc;
        u16* op = Opart + (pbase + row_g) * HD;
        #pragma unroll
        for (int db = 0; db < 8; ++db)
            op[db*16 + c] = f2bf(accO[db][r]);
        if (c == 0) ml[pbase + row_g] = make_float2(mr, lr);
    }
}

// ---------------------------------------------------------------------------
// Merge the two split-s partials -> q slot of qkv (bf16).
// idx over NH*T*HD; 128-thread groups share (h,t).
// ---------------------------------------------------------------------------
__global__ __launch_bounds__(256) void attn_combine(
    const u16* __restrict__ Opart, const float2* __restrict__ ml,
    u16* __restrict__ qkv)
{
    const int idx = blockIdx.x * 256 + threadIdx.x;
    const int d = idx & (HD - 1);
    const int t = (idx >> 7) & (T_TOK - 1);
    const int h = idx >> 18;
    const size_t iA = (size_t)h * T_TOK + t;
    const size_t iB = (size_t)(NH + h) * T_TOK + t;
    const float2 a = ml[iA];
    const float2 b = ml[iB];
    const float Cs = 0.12751744f;
    const float mM = fmaxf(a.x, b.x);
    const float wA = exp2f((a.x - mM) * Cs);
    const float wB = exp2f((b.x - mM) * Cs);
    const float OA = bf2f(Opart[iA * HD + d]);
    const float OB = bf2f(Opart[iB * HD + d]);
    const float o = (wA * OA + wB * OB) / (wA * a.y + wB * b.y);
    qkv[(size_t)t * QKV_N + h * HD + d] = f2bf(o);
}

// ---------------------------------------------------------------------------
extern "C" void kernel_launch(void* const* d_in, const int* in_sizes, int n_in,
                              void* d_out, int out_size, void* d_ws, size_t ws_size,
                              hipStream_t stream)
{
    const float* hidden    = (const float*)d_in[0];   // T x HID
    const int*   positions = (const int*)  d_in[1];   // T
    const float* qkv_w     = (const float*)d_in[2];   // 4096 x 2048
    const float* o_w       = (const float*)d_in[3];   // 2048 x 2048
    const float* q_norm_w  = (const float*)d_in[4];   // 128
    const float* k_norm_w  = (const float*)d_in[5];   // 128
    float* out = (float*)d_out;                       // T x HID (f32)

    // ws: [qkvbf 16MB][wbf 16MB][abf 8MB][vt 4MB] = 44 MB
    // wbf/abf are dead after GEMM1 -> reused for attn partials (Opart/ml),
    // then abf is reused again for bf16 o_w (after combine).
    u16* qkvbf = (u16*)d_ws;
    u16* wbf   = qkvbf + (size_t)T_TOK * QKV_N;
    u16* abf   = wbf   + (size_t)QKV_N * HID;
    u16* vtb   = abf   + (size_t)T_TOK * HID;

    cvt_f32_bf16<<<(T_TOK*HID)/2048, 256, 0, stream>>>(hidden, abf);
    cvt_f32_bf16<<<(QKV_N*HID)/2048, 256, 0, stream>>>(qkv_w, wbf);

    // 1) qkv(bf16) = hidden @ qkv_w^T
    gemm_bt_bf16<true><<<dim3(QKV_N/128, T_TOK/128), 256, 0, stream>>>(
        abf, wbf, qkvbf, HID, HID, HID, QKV_N);

    // 2) rmsnorm + rope on q,k
    norm_rope<<<dim3(T_TOK, NH + NKV), 128, 0, stream>>>(
        qkvbf, positions, q_norm_w, k_norm_w);

    // 2b) vt[kv][d][t] = V^T
    v_transpose<<<dim3(T_TOK/32, HD/32, NKV), 256, 0, stream>>>(qkvbf, vtb);

    // 3) split-s MFMA flash attention -> partials (Opart in wbf, ml in abf)
    attn_mfma<<<dim3(T_TOK/64, NH, 2), 256, 0, stream>>>(
        qkvbf, vtb, wbf, (float2*)abf);

    // 3b) combine partials -> q slots of qkv
    attn_combine<<<(NH*T_TOK*HD)/256, 256, 0, stream>>>(
        wbf, (const float2*)abf, qkvbf);

    // 4) out(f32) = o @ o_w^T  (o_w bf16 into abf, dead after combine)
    cvt_f32_bf16<<<(HID*HID)/2048, 256, 0, stream>>>(o_w, abf);
    gemm_bt_bf16<false><<<dim3(HID/128, T_TOK/128), 256, 0, stream>>>(
        qkvbf, abf, out, HID, QKV_N, HID, HID);
}

// Round 8
// 327.569 us; speedup vs baseline: 1.0555x; 1.0555x over previous
//
#include <hip/hip_runtime.h>
#include <math.h>

// Qwen3Attention: T=2048, HID=2048, H=16, KV=8, D=128
#define T_TOK 2048
#define HID 2048
#define NH 16
#define NKV 8
#define HD 128
#define QKV_N 4096
#define EPS 1e-6f

typedef unsigned short u16;
typedef unsigned int   u32;
typedef __attribute__((ext_vector_type(8))) u16   u16x8;
typedef __attribute__((ext_vector_type(8))) short short8;
typedef __attribute__((ext_vector_type(4))) float floatx4;
typedef __attribute__((ext_vector_type(4))) u32   u32x4;

__device__ __forceinline__ u16 f2bf(float x) {           // RNE f32->bf16
    u32 u = __float_as_uint(x);
    u = (u + 0x7fffu + ((u >> 16) & 1u)) >> 16;
    return (u16)u;
}
__device__ __forceinline__ float bf2f(u16 h) {
    return __uint_as_float(((u32)h) << 16);
}

// ---------------------------------------------------------------------------
// f32 -> bf16 elementwise (8 elems/thread). n must be a multiple of 2048.
// ---------------------------------------------------------------------------
__global__ __launch_bounds__(256) void cvt_f32_bf16(
    const float* __restrict__ in, u16* __restrict__ out)
{
    const size_t i = ((size_t)blockIdx.x * 256 + threadIdx.x) * 8;
    float4 a = *(const float4*)(in + i);
    float4 b = *(const float4*)(in + i + 4);
    u16x8 o;
    o[0] = f2bf(a.x); o[1] = f2bf(a.y); o[2] = f2bf(a.z); o[3] = f2bf(a.w);
    o[4] = f2bf(b.x); o[5] = f2bf(b.y); o[6] = f2bf(b.z); o[7] = f2bf(b.w);
    *(u16x8*)(out + i) = o;
}

// ---------------------------------------------------------------------------
// bf16 MFMA GEMM (m97 pattern): C[M,N] = A[M,K]*B[N,K]^T
// 128x128 tile, BK=32, 256 thr; global_load_lds width=16 staging.
// ---------------------------------------------------------------------------
template<bool OUT_BF16>
__global__ __launch_bounds__(256) void gemm_bt_bf16(
    const u16* __restrict__ A, const u16* __restrict__ B,
    void* __restrict__ Cv, int K, int lda, int ldb, int ldc)
{
    __shared__ short As[128 * 32];
    __shared__ short Bs[128 * 32];

    const int tid = threadIdx.x;
    const int w   = tid >> 6;
    const int l   = tid & 63;
    const int m0  = blockIdx.y * 128;
    const int n0  = blockIdx.x * 128;
    const int wm  = (w >> 1) * 64;
    const int wn  = (w & 1) * 64;
    const int lm  = l & 15;
    const int ko8 = (l >> 4) * 8;

    const u16* gA0 = A + (size_t)(m0      + (tid >> 2)) * lda + (tid & 3) * 8;
    const u16* gA1 = A + (size_t)(m0 + 64 + (tid >> 2)) * lda + (tid & 3) * 8;
    const u16* gB0 = B + (size_t)(n0      + (tid >> 2)) * ldb + (tid & 3) * 8;
    const u16* gB1 = B + (size_t)(n0 + 64 + (tid >> 2)) * ldb + (tid & 3) * 8;
    short* lA0 = As + w * 512;
    short* lA1 = As + 2048 + w * 512;
    short* lB0 = Bs + w * 512;
    short* lB1 = Bs + 2048 + w * 512;

    floatx4 acc[4][4];
    #pragma unroll
    for (int i = 0; i < 4; ++i)
        #pragma unroll
        for (int j = 0; j < 4; ++j) acc[i][j] = (floatx4){0.f, 0.f, 0.f, 0.f};

    for (int k0 = 0; k0 < K; k0 += 32) {
        __syncthreads();
        __builtin_amdgcn_global_load_lds(
            (const __attribute__((address_space(1))) u32*)(gA0 + k0),
            (__attribute__((address_space(3))) u32*)lA0, 16, 0, 0);
        __builtin_amdgcn_global_load_lds(
            (const __attribute__((address_space(1))) u32*)(gA1 + k0),
            (__attribute__((address_space(3))) u32*)lA1, 16, 0, 0);
        __builtin_amdgcn_global_load_lds(
            (const __attribute__((address_space(1))) u32*)(gB0 + k0),
            (__attribute__((address_space(3))) u32*)lB0, 16, 0, 0);
        __builtin_amdgcn_global_load_lds(
            (const __attribute__((address_space(1))) u32*)(gB1 + k0),
            (__attribute__((address_space(3))) u32*)lB1, 16, 0, 0);
        __syncthreads();

        short8 af[4], bfr[4];
        #pragma unroll
        for (int i = 0; i < 4; ++i)
            af[i] = *(const short8*)(As + (wm + i * 16 + lm) * 32 + ko8);
        #pragma unroll
        for (int j = 0; j < 4; ++j)
            bfr[j] = *(const short8*)(Bs + (wn + j * 16 + lm) * 32 + ko8);
        #pragma unroll
        for (int i = 0; i < 4; ++i)
            #pragma unroll
            for (int j = 0; j < 4; ++j)
                acc[i][j] = __builtin_amdgcn_mfma_f32_16x16x32_bf16(
                    af[i], bfr[j], acc[i][j], 0, 0, 0);
    }

    const int r0 = (l >> 4) * 4;
    #pragma unroll
    for (int i = 0; i < 4; ++i)
        #pragma unroll
        for (int j = 0; j < 4; ++j)
            #pragma unroll
            for (int r = 0; r < 4; ++r) {
                const int row = m0 + wm + i * 16 + r0 + r;
                const int col = n0 + wn + j * 16 + lm;
                if (OUT_BF16)
                    ((u16*)Cv)[(size_t)row * ldc + col] = f2bf(acc[i][j][r]);
                else
                    ((float*)Cv)[(size_t)row * ldc + col] = acc[i][j][r];
            }
}

// ---------------------------------------------------------------------------
// RMSNorm + RoPE, in-place on bf16 qkv. grid=(T, NH+NKV), 128 thr.
// ---------------------------------------------------------------------------
__global__ __launch_bounds__(128) void norm_rope(
    u16* __restrict__ qkv, const int* __restrict__ positions,
    const float* __restrict__ qw, const float* __restrict__ kw)
{
    const int t   = blockIdx.x;
    const int hh  = blockIdx.y;
    const int tid = threadIdx.x;

    u16* p; const float* w;
    if (hh < NH) { p = qkv + (size_t)t*QKV_N + hh*HD;              w = qw; }
    else         { p = qkv + (size_t)t*QKV_N + NH*HD + (hh-NH)*HD; w = kw; }

    float x = bf2f(p[tid]);

    __shared__ float red[2];
    float ss = x * x;
    #pragma unroll
    for (int o = 32; o > 0; o >>= 1) ss += __shfl_down(ss, o);
    if ((tid & 63) == 0) red[tid >> 6] = ss;
    __syncthreads();
    const float var = (red[0] + red[1]) * (1.0f / (float)HD);
    float xn = x * rsqrtf(var + EPS) * w[tid];

    __shared__ float sx[HD];
    sx[tid] = xn;
    __syncthreads();

    const int   pos = positions[t];
    const int   i   = tid & 63;
    const float inv_freq = exp2f(-(float)i * 0.311430758895690f); // log2(1e6)/64
    const float ang = (float)pos * inv_freq;
    const float s = sinf(ang);   // NOTE: sincosf ptr order trap (r1/r2 bug)
    const float c = cosf(ang);

    float out;
    if (tid < 64) out = sx[i]      * c - sx[i + 64] * s;
    else          out = sx[i + 64] * c + sx[i]      * s;
    p[tid] = f2bf(out);
}

// ---------------------------------------------------------------------------
// K pack: tile-contiguous, XOR-swizzled LDS image.
// Kp[(kvh*32+tile)*64 + r][16B-chunk o] = K[tile*64+r][chunk o ^ (r&15)]
// grid (32, NKV), 256 thr. Reads within-row permuted (same lines); writes
// fully contiguous.
// ---------------------------------------------------------------------------
__global__ __launch_bounds__(256) void k_pack(
    const u16* __restrict__ qkv, u16* __restrict__ Kp)
{
    const int tile = blockIdx.x, kvh = blockIdx.y, tid = threadIdx.x;
    const int r  = tid >> 2;           // 0..63
    const int og = (tid & 3) * 4;      // chunk group
    const u16* src = qkv + (size_t)(tile*64 + r)*QKV_N + NH*HD + kvh*HD;
    u16* dst = Kp + ((size_t)(kvh*32 + tile)*64 + r) * 128;
    #pragma unroll
    for (int i = 0; i < 4; ++i) {
        const int o = og + i;
        *(u16x8*)(dst + o*8) = *(const u16x8*)(src + (o ^ (r & 15))*8);
    }
}

// ---------------------------------------------------------------------------
// V pack: transpose + XOR-swizzled LDS image.
// Vtp[(kvh*32+tile)*128 + d][16B-chunk o] = V[tile*64 + (o^(d&7))*8 + j][d]
// grid (32, NKV), 256 thr, LDS tile transpose.
// ---------------------------------------------------------------------------
__global__ __launch_bounds__(256) void v_pack(
    const u16* __restrict__ qkv, u16* __restrict__ Vtp)
{
    const int tile = blockIdx.x, kvh = blockIdx.y, tid = threadIdx.x;
    __shared__ u16 tl[64][136];        // [t][d], pad
    const int t  = tid >> 2;
    const int c0 = (tid & 3) * 32;
    const u16* src = qkv + (size_t)(tile*64 + t)*QKV_N + NH*HD + NKV*HD + kvh*HD + c0;
    #pragma unroll
    for (int p = 0; p < 4; ++p)
        *(u16x8*)(&tl[t][c0 + p*8]) = *(const u16x8*)(src + p*8);
    __syncthreads();
    u16* dstb = Vtp + (size_t)(kvh*32 + tile) * 128 * 64;
    #pragma unroll
    for (int i = 0; i < 4; ++i) {
        const int id = tid*4 + i;      // over (d,o): 128*8 = 1024 chunks
        const int d = id >> 3;
        const int o = id & 7;
        const int sb = (o ^ (d & 7)) * 8;
        u16x8 v;
        #pragma unroll
        for (int j = 0; j < 8; ++j) v[j] = tl[sb + j][d];
        *(u16x8*)(dstb + d*64 + o*8) = v;
    }
}

// ---------------------------------------------------------------------------
// Split-s MFMA flash attention, DMA-staged from packed K/Vt images.
// grid = (T/64, NH, 2); 256 thr = 4 waves. Wave w owns queries 16w..16w+15
// (Q fragments in registers). S^T = K·Q^T -> query idx at C/D col=lane&15.
// K/Vt tiles DMA'd via global_load_lds (contiguous 1KB/issue); fragment
// ds_reads hit the XOR-swizzled layout conflict-free. Unnormalized partials.
// ---------------------------------------------------------------------------
__global__ __launch_bounds__(256) void attn_mfma(
    const u16* __restrict__ qkv, const u16* __restrict__ Kp,
    const u16* __restrict__ Vtp,
    u16* __restrict__ Opart, float2* __restrict__ ml)
{
    const int qt   = (int)(gridDim.x - 1) - (int)blockIdx.x;  // heavy first
    const int h    = blockIdx.y;
    const int half = blockIdx.z;
    const int kvh  = h >> 1;
    const int t0   = qt * 64;
    const int tid  = threadIdx.x;
    const int w    = tid >> 6;
    const int l    = tid & 63;
    const int q4   = l >> 4;       // quad group 0..3
    const int c    = l & 15;       // col (query) index within 16

    __shared__ short Ks[64 * 128];   // 16 KB DMA image (swizzled rows)
    __shared__ short Vts[128 * 64];  // 16 KB DMA image -> 32 KB total

    // ---- Q fragments in registers: bq[kk] = Q[w*16+c][kk*32+q4*8 ..+8] ----
    short8 bq[4];
    {
        const u16* qrow = qkv + (size_t)(t0 + w*16 + c) * QKV_N + h*HD;
        #pragma unroll
        for (int kk = 0; kk < 4; ++kk)
            bq[kk] = *(const short8*)(qrow + kk*32 + q4*8);
    }

    float m_run = -3.0e38f, l_run = 0.f;
    floatx4 accO[8];
    #pragma unroll
    for (int db = 0; db < 8; ++db) accO[db] = (floatx4){0.f, 0.f, 0.f, 0.f};

    const float Cs = 0.12751744f;   // (1/sqrt(128)) * log2(e)

    const int nt  = qt + 1;
    const int nh0 = (nt + 1) >> 1;          // half0 gets ceil, half1 diagonal
    const int tlo = half ? nh0 : 0;
    const int thi = half ? nt  : nh0;

    for (int tile = tlo; tile < thi; ++tile) {
        __syncthreads();   // prev iteration's LDS reads complete
        {   // ---- DMA stage K & Vt images (wave w: bytes [w*4K, w*4K+4K)) ----
            const u16* gk = Kp  + (size_t)(kvh*32 + tile)*8192 + w*2048 + l*8;
            const u16* gv = Vtp + (size_t)(kvh*32 + tile)*8192 + w*2048 + l*8;
            short* lk = Ks  + w*2048;
            short* lv = Vts + w*2048;
            #pragma unroll
            for (int i = 0; i < 4; ++i) {
                __builtin_amdgcn_global_load_lds(
                    (const __attribute__((address_space(1))) u32*)(gk + i*512),
                    (__attribute__((address_space(3))) u32*)(lk + i*512), 16, 0, 0);
                __builtin_amdgcn_global_load_lds(
                    (const __attribute__((address_space(1))) u32*)(gv + i*512),
                    (__attribute__((address_space(3))) u32*)(lv + i*512), 16, 0, 0);
            }
        }
        __syncthreads();

        // ---- S^T = K Q^T : accS[sb] = s rows [16sb,16sb+16), q col 16w+c ----
        // ak phys: row*128 + ((kk*4+q4)^c)*8   (row&15 == c)
        floatx4 accS[4];
        #pragma unroll
        for (int sb = 0; sb < 4; ++sb) accS[sb] = (floatx4){0.f, 0.f, 0.f, 0.f};
        #pragma unroll
        for (int kk = 0; kk < 4; ++kk) {
            #pragma unroll
            for (int sb = 0; sb < 4; ++sb) {
                short8 ak = *(const short8*)(Ks + (sb*16 + c)*128 + ((kk*4 + q4) ^ c)*8);
                accS[sb] = __builtin_amdgcn_mfma_f32_16x16x32_bf16(ak, bq[kk], accS[sb], 0, 0, 0);
            }
        }

        // ---- causal mask on the diagonal tile (s0 == t0 there) ----
        if (tile == qt) {
            #pragma unroll
            for (int sb = 0; sb < 4; ++sb)
                #pragma unroll
                for (int r = 0; r < 4; ++r) {
                    const int s_loc = sb*16 + q4*4 + r;
                    const int t_loc = w*16 + c;
                    if (s_loc > t_loc) accS[sb][r] = -1.0e30f;
                }
        }

        // ---- online softmax (per query col c) ----
        float mt = -3.0e38f;
        #pragma unroll
        for (int sb = 0; sb < 4; ++sb)
            #pragma unroll
            for (int r = 0; r < 4; ++r) mt = fmaxf(mt, accS[sb][r]);
        mt = fmaxf(mt, __shfl_xor(mt, 16));
        mt = fmaxf(mt, __shfl_xor(mt, 32));

        const float m_new = fmaxf(m_run, mt);
        const float alpha = exp2f((m_run - m_new) * Cs);  // 0 on first tile
        m_run = m_new;

        float P[4][4];
        float lsum = 0.f;
        #pragma unroll
        for (int sb = 0; sb < 4; ++sb)
            #pragma unroll
            for (int r = 0; r < 4; ++r) {
                const float e = exp2f((accS[sb][r] - m_new) * Cs);
                P[sb][r] = e;
                lsum += e;
            }
        lsum += __shfl_xor(lsum, 16);
        lsum += __shfl_xor(lsum, 32);
        l_run = l_run * alpha + lsum;

        // ---- rescale O by alpha (alpha per col c; O rows are 4q+r) ----
        #pragma unroll
        for (int r = 0; r < 4; ++r) {
            const float ar = __shfl(alpha, (l & 48) | (q4*4 + r));
            #pragma unroll
            for (int db = 0; db < 8; ++db) accO[db][r] *= ar;
        }

        // ---- pack P to bf16 pairs ----
        u32 Pp[4][2];
        #pragma unroll
        for (int sb = 0; sb < 4; ++sb)
            #pragma unroll
            for (int p = 0; p < 2; ++p)
                Pp[sb][p] = (u32)f2bf(P[sb][2*p]) | ((u32)f2bf(P[sb][2*p+1]) << 16);

        // ---- PV: O[m][d] += P[m][s] * Vt[d][s] ----
        // bv phys: d'*64 + ((k2*4+q4)^(c&7))*8   (d' = db*16+c, d'&7 == c&7)
        const int src0 = ((2*q4    ) & 3) * 16 + c;
        const int src1 = ((2*q4 + 1) & 3) * 16 + c;
        const bool hiq = q4 >= 2;
        #pragma unroll
        for (int k2 = 0; k2 < 2; ++k2) {
            u32 x0 = __shfl(Pp[2*k2][0],   src0), y0 = __shfl(Pp[2*k2+1][0], src0);
            u32 x1 = __shfl(Pp[2*k2][1],   src0), y1 = __shfl(Pp[2*k2+1][1], src0);
            u32 x2 = __shfl(Pp[2*k2][0],   src1), y2 = __shfl(Pp[2*k2+1][0], src1);
            u32 x3 = __shfl(Pp[2*k2][1],   src1), y3 = __shfl(Pp[2*k2+1][1], src1);
            u32x4 av;
            av.x = hiq ? y0 : x0;  av.y = hiq ? y1 : x1;
            av.z = hiq ? y2 : x2;  av.w = hiq ? y3 : x3;
            const short8 aP = __builtin_bit_cast(short8, av);
            #pragma unroll
            for (int db = 0; db < 8; ++db) {
                short8 bv = *(const short8*)(Vts + (db*16 + c)*64 + (((k2*4 + q4) ^ (c & 7)))*8);
                accO[db] = __builtin_amdgcn_mfma_f32_16x16x32_bf16(aP, bv, accO[db], 0, 0, 0);
            }
        }
    }

    // ---- write UNNORMALIZED partial + (m,l) per query row ----
    const size_t pbase = (size_t)(half * NH + h) * T_TOK;
    #pragma unroll
    for (int r = 0; r < 4; ++r) {
        const int qloc = q4*4 + r;
        const float mr = __shfl(m_run, (l & 48) | qloc);
        const float lr = __shfl(l_run, (l & 48) | qloc);
        const int row_g = t0 + w*16 + qloc;
        u16* op = Opart + (pbase + row_g) * HD;
        #pragma unroll
        for (int db = 0; db < 8; ++db)
            op[db*16 + c] = f2bf(accO[db][r]);
        if (c == 0) ml[pbase + row_g] = make_float2(mr, lr);
    }
}

// ---------------------------------------------------------------------------
// Merge the two split-s partials -> q slot of qkv (bf16).
// ---------------------------------------------------------------------------
__global__ __launch_bounds__(256) void attn_combine(
    const u16* __restrict__ Opart, const float2* __restrict__ ml,
    u16* __restrict__ qkv)
{
    const int idx = blockIdx.x * 256 + threadIdx.x;
    const int d = idx & (HD - 1);
    const int t = (idx >> 7) & (T_TOK - 1);
    const int h = idx >> 18;
    const size_t iA = (size_t)h * T_TOK + t;
    const size_t iB = (size_t)(NH + h) * T_TOK + t;
    const float2 a = ml[iA];
    const float2 b = ml[iB];
    const float Cs = 0.12751744f;
    const float mM = fmaxf(a.x, b.x);
    const float wA = exp2f((a.x - mM) * Cs);
    const float wB = exp2f((b.x - mM) * Cs);
    const float OA = bf2f(Opart[iA * HD + d]);
    const float OB = bf2f(Opart[iB * HD + d]);
    const float o = (wA * OA + wB * OB) / (wA * a.y + wB * b.y);
    qkv[(size_t)t * QKV_N + h * HD + d] = f2bf(o);
}

// ---------------------------------------------------------------------------
extern "C" void kernel_launch(void* const* d_in, const int* in_sizes, int n_in,
                              void* d_out, int out_size, void* d_ws, size_t ws_size,
                              hipStream_t stream)
{
    const float* hidden    = (const float*)d_in[0];   // T x HID
    const int*   positions = (const int*)  d_in[1];   // T
    const float* qkv_w     = (const float*)d_in[2];   // 4096 x 2048
    const float* o_w       = (const float*)d_in[3];   // 2048 x 2048
    const float* q_norm_w  = (const float*)d_in[4];   // 128
    const float* k_norm_w  = (const float*)d_in[5];   // 128
    float* out = (float*)d_out;                       // T x HID (f32)

    // ws: [qkvbf 16MB][wbf 16MB][abf 8MB][Kp 4MB][Vtp 4MB] = 48 MB
    // wbf -> Opart during attn; abf -> hidden bf16, then ml, then o_w bf16.
    u16* qkvbf = (u16*)d_ws;
    u16* wbf   = qkvbf + (size_t)T_TOK * QKV_N;
    u16* abf   = wbf   + (size_t)QKV_N * HID;
    u16* kpb   = abf   + (size_t)T_TOK * HID;
    u16* vpb   = kpb   + (size_t)NKV * T_TOK * HD;

    cvt_f32_bf16<<<(T_TOK*HID)/2048, 256, 0, stream>>>(hidden, abf);
    cvt_f32_bf16<<<(QKV_N*HID)/2048, 256, 0, stream>>>(qkv_w, wbf);

    // 1) qkv(bf16) = hidden @ qkv_w^T
    gemm_bt_bf16<true><<<dim3(QKV_N/128, T_TOK/128), 256, 0, stream>>>(
        abf, wbf, qkvbf, HID, HID, HID, QKV_N);

    // 2) rmsnorm + rope on q,k
    norm_rope<<<dim3(T_TOK, NH + NKV), 128, 0, stream>>>(
        qkvbf, positions, q_norm_w, k_norm_w);

    // 2b) pack K and V^T into tile-contiguous swizzled DMA images
    k_pack<<<dim3(T_TOK/64, NKV), 256, 0, stream>>>(qkvbf, kpb);
    v_pack<<<dim3(T_TOK/64, NKV), 256, 0, stream>>>(qkvbf, vpb);

    // 3) split-s MFMA flash attention -> partials (Opart in wbf, ml in abf)
    attn_mfma<<<dim3(T_TOK/64, NH, 2), 256, 0, stream>>>(
        qkvbf, kpb, vpb, wbf, (float2*)abf);

    // 3b) combine partials -> q slots of qkv
    attn_combine<<<(NH*T_TOK*HD)/256, 256, 0, stream>>>(
        wbf, (const float2*)abf, qkvbf);

    // 4) out(f32) = o @ o_w^T  (o_w bf16 into abf, dead after combine)
    cvt_f32_bf16<<<(HID*HID)/2048, 256, 0, stream>>>(o_w, abf);
    gemm_bt_bf16<false><<<dim3(HID/128, T_TOK/128), 256, 0, stream>>>(
        qkvbf, abf, out, HID, QKV_N, HID, HID);
}

// Round 9
// 291.518 us; speedup vs baseline: 1.1860x; 1.1237x over previous
//
#include <hip/hip_runtime.h>
#include <math.h>

// Qwen3Attention: T=2048, HID=2048, H=16, KV=8, D=128
#define T_TOK 2048
#define HID 2048
#define NH 16
#define NKV 8
#define HD 128
#define QKV_N 4096
#define EPS 1e-6f

typedef unsigned short u16;
typedef unsigned int   u32;
typedef __attribute__((ext_vector_type(8))) u16   u16x8;
typedef __attribute__((ext_vector_type(8))) short short8;
typedef __attribute__((ext_vector_type(4))) float floatx4;
typedef __attribute__((ext_vector_type(4))) u32   u32x4;

__device__ __forceinline__ u16 f2bf(float x) {           // RNE f32->bf16
    u32 u = __float_as_uint(x);
    u = (u + 0x7fffu + ((u >> 16) & 1u)) >> 16;
    return (u16)u;
}
__device__ __forceinline__ float bf2f(u16 h) {
    return __uint_as_float(((u32)h) << 16);
}

// ---------------------------------------------------------------------------
// f32 -> bf16 elementwise (8 elems/thread). n must be a multiple of 2048.
// ---------------------------------------------------------------------------
__global__ __launch_bounds__(256) void cvt_f32_bf16(
    const float* __restrict__ in, u16* __restrict__ out)
{
    const size_t i = ((size_t)blockIdx.x * 256 + threadIdx.x) * 8;
    float4 a = *(const float4*)(in + i);
    float4 b = *(const float4*)(in + i + 4);
    u16x8 o;
    o[0] = f2bf(a.x); o[1] = f2bf(a.y); o[2] = f2bf(a.z); o[3] = f2bf(a.w);
    o[4] = f2bf(b.x); o[5] = f2bf(b.y); o[6] = f2bf(b.z); o[7] = f2bf(b.w);
    *(u16x8*)(out + i) = o;
}

// ---------------------------------------------------------------------------
// bf16 MFMA GEMM (m97 pattern): C[M,N] = A[M,K]*B[N,K]^T
// 128x128 tile, BK=32, 256 thr; global_load_lds width=16 staging.
// ---------------------------------------------------------------------------
template<bool OUT_BF16>
__global__ __launch_bounds__(256) void gemm_bt_bf16(
    const u16* __restrict__ A, const u16* __restrict__ B,
    void* __restrict__ Cv, int K, int lda, int ldb, int ldc)
{
    __shared__ short As[128 * 32];
    __shared__ short Bs[128 * 32];

    const int tid = threadIdx.x;
    const int w   = tid >> 6;
    const int l   = tid & 63;
    const int m0  = blockIdx.y * 128;
    const int n0  = blockIdx.x * 128;
    const int wm  = (w >> 1) * 64;
    const int wn  = (w & 1) * 64;
    const int lm  = l & 15;
    const int ko8 = (l >> 4) * 8;

    const u16* gA0 = A + (size_t)(m0      + (tid >> 2)) * lda + (tid & 3) * 8;
    const u16* gA1 = A + (size_t)(m0 + 64 + (tid >> 2)) * lda + (tid & 3) * 8;
    const u16* gB0 = B + (size_t)(n0      + (tid >> 2)) * ldb + (tid & 3) * 8;
    const u16* gB1 = B + (size_t)(n0 + 64 + (tid >> 2)) * ldb + (tid & 3) * 8;
    short* lA0 = As + w * 512;
    short* lA1 = As + 2048 + w * 512;
    short* lB0 = Bs + w * 512;
    short* lB1 = Bs + 2048 + w * 512;

    floatx4 acc[4][4];
    #pragma unroll
    for (int i = 0; i < 4; ++i)
        #pragma unroll
        for (int j = 0; j < 4; ++j) acc[i][j] = (floatx4){0.f, 0.f, 0.f, 0.f};

    for (int k0 = 0; k0 < K; k0 += 32) {
        __syncthreads();
        __builtin_amdgcn_global_load_lds(
            (const __attribute__((address_space(1))) u32*)(gA0 + k0),
            (__attribute__((address_space(3))) u32*)lA0, 16, 0, 0);
        __builtin_amdgcn_global_load_lds(
            (const __attribute__((address_space(1))) u32*)(gA1 + k0),
            (__attribute__((address_space(3))) u32*)lA1, 16, 0, 0);
        __builtin_amdgcn_global_load_lds(
            (const __attribute__((address_space(1))) u32*)(gB0 + k0),
            (__attribute__((address_space(3))) u32*)lB0, 16, 0, 0);
        __builtin_amdgcn_global_load_lds(
            (const __attribute__((address_space(1))) u32*)(gB1 + k0),
            (__attribute__((address_space(3))) u32*)lB1, 16, 0, 0);
        __syncthreads();

        short8 af[4], bfr[4];
        #pragma unroll
        for (int i = 0; i < 4; ++i)
            af[i] = *(const short8*)(As + (wm + i * 16 + lm) * 32 + ko8);
        #pragma unroll
        for (int j = 0; j < 4; ++j)
            bfr[j] = *(const short8*)(Bs + (wn + j * 16 + lm) * 32 + ko8);
        #pragma unroll
        for (int i = 0; i < 4; ++i)
            #pragma unroll
            for (int j = 0; j < 4; ++j)
                acc[i][j] = __builtin_amdgcn_mfma_f32_16x16x32_bf16(
                    af[i], bfr[j], acc[i][j], 0, 0, 0);
    }

    const int r0 = (l >> 4) * 4;
    #pragma unroll
    for (int i = 0; i < 4; ++i)
        #pragma unroll
        for (int j = 0; j < 4; ++j)
            #pragma unroll
            for (int r = 0; r < 4; ++r) {
                const int row = m0 + wm + i * 16 + r0 + r;
                const int col = n0 + wn + j * 16 + lm;
                if (OUT_BF16)
                    ((u16*)Cv)[(size_t)row * ldc + col] = f2bf(acc[i][j][r]);
                else
                    ((float*)Cv)[(size_t)row * ldc + col] = acc[i][j][r];
            }
}

// ---------------------------------------------------------------------------
// RMSNorm + RoPE, in-place on bf16 qkv. grid=(T, NH+NKV), 128 thr.
// ---------------------------------------------------------------------------
__global__ __launch_bounds__(128) void norm_rope(
    u16* __restrict__ qkv, const int* __restrict__ positions,
    const float* __restrict__ qw, const float* __restrict__ kw)
{
    const int t   = blockIdx.x;
    const int hh  = blockIdx.y;
    const int tid = threadIdx.x;

    u16* p; const float* w;
    if (hh < NH) { p = qkv + (size_t)t*QKV_N + hh*HD;              w = qw; }
    else         { p = qkv + (size_t)t*QKV_N + NH*HD + (hh-NH)*HD; w = kw; }

    float x = bf2f(p[tid]);

    __shared__ float red[2];
    float ss = x * x;
    #pragma unroll
    for (int o = 32; o > 0; o >>= 1) ss += __shfl_down(ss, o);
    if ((tid & 63) == 0) red[tid >> 6] = ss;
    __syncthreads();
    const float var = (red[0] + red[1]) * (1.0f / (float)HD);
    float xn = x * rsqrtf(var + EPS) * w[tid];

    __shared__ float sx[HD];
    sx[tid] = xn;
    __syncthreads();

    const int   pos = positions[t];
    const int   i   = tid & 63;
    const float inv_freq = exp2f(-(float)i * 0.311430758895690f); // log2(1e6)/64
    const float ang = (float)pos * inv_freq;
    const float s = sinf(ang);   // NOTE: sincosf ptr order trap (r1/r2 bug)
    const float c = cosf(ang);

    float out;
    if (tid < 64) out = sx[i]      * c - sx[i + 64] * s;
    else          out = sx[i + 64] * c + sx[i]      * s;
    p[tid] = f2bf(out);
}

// ---------------------------------------------------------------------------
// K pack: tile-contiguous, XOR-swizzled LDS image.
// Kp[(kvh*32+tile)*64 + r][16B-chunk o] = K[tile*64+r][chunk o ^ (r&15)]
// ---------------------------------------------------------------------------
__global__ __launch_bounds__(256) void k_pack(
    const u16* __restrict__ qkv, u16* __restrict__ Kp)
{
    const int tile = blockIdx.x, kvh = blockIdx.y, tid = threadIdx.x;
    const int r  = tid >> 2;           // 0..63
    const int og = (tid & 3) * 4;      // chunk group
    const u16* src = qkv + (size_t)(tile*64 + r)*QKV_N + NH*HD + kvh*HD;
    u16* dst = Kp + ((size_t)(kvh*32 + tile)*64 + r) * 128;
    #pragma unroll
    for (int i = 0; i < 4; ++i) {
        const int o = og + i;
        *(u16x8*)(dst + o*8) = *(const u16x8*)(src + (o ^ (r & 15))*8);
    }
}

// ---------------------------------------------------------------------------
// V pack: transpose + XOR-swizzled LDS image.
// Vtp[(kvh*32+tile)*128 + d][16B-chunk o] = V[tile*64 + (o^(d&7))*8 + j][d]
// ---------------------------------------------------------------------------
__global__ __launch_bounds__(256) void v_pack(
    const u16* __restrict__ qkv, u16* __restrict__ Vtp)
{
    const int tile = blockIdx.x, kvh = blockIdx.y, tid = threadIdx.x;
    __shared__ u16 tl[64][136];        // [t][d], pad
    const int t  = tid >> 2;
    const int c0 = (tid & 3) * 32;
    const u16* src = qkv + (size_t)(tile*64 + t)*QKV_N + NH*HD + NKV*HD + kvh*HD + c0;
    #pragma unroll
    for (int p = 0; p < 4; ++p)
        *(u16x8*)(&tl[t][c0 + p*8]) = *(const u16x8*)(src + p*8);
    __syncthreads();
    u16* dstb = Vtp + (size_t)(kvh*32 + tile) * 128 * 64;
    #pragma unroll
    for (int i = 0; i < 4; ++i) {
        const int id = tid*4 + i;      // over (d,o): 128*8 = 1024 chunks
        const int d = id >> 3;
        const int o = id & 7;
        const int sb = (o ^ (d & 7)) * 8;
        u16x8 v;
        #pragma unroll
        for (int j = 0; j < 8; ++j) v[j] = tl[sb + j][d];
        *(u16x8*)(dstb + d*64 + o*8) = v;
    }
}

// ---------------------------------------------------------------------------
// Head-pair-merged split-s MFMA flash attention.
// grid = 512 blocks x 512 thr (8 waves). Decode: z=id>>8, kvh=id&7,
// bid=(id&255)>>3, qt = z ? bid : 31-bid  (pairs heavy z=0 with light z=1 on
// the same CU -> ~16.5 tile-iters/CU; all 512 blocks co-resident, 2/CU).
// Waves 0-3 compute head 2*kvh, waves 4-7 head 2*kvh+1, sharing one K/Vt
// LDS image per tile (DMA'd once). Wave w owns queries 16*(w&3)+c of its
// head (Q fragments in registers). S^T = K·Q^T -> query idx at col=lane&15.
// Unnormalized partials (O bf16, m/l f32) merged by attn_combine.
// ---------------------------------------------------------------------------
__global__ __launch_bounds__(512) void attn_mfma(
    const u16* __restrict__ qkv, const u16* __restrict__ Kp,
    const u16* __restrict__ Vtp,
    u16* __restrict__ Opart, float2* __restrict__ ml)
{
    const int id   = blockIdx.x;
    const int half = id >> 8;
    const int kvh  = id & 7;
    const int bid  = (id & 255) >> 3;              // 0..31
    const int qt   = half ? bid : 31 - bid;
    const int t0   = qt * 64;
    const int tid  = threadIdx.x;
    const int w    = tid >> 6;      // 0..7
    const int l    = tid & 63;
    const int q4   = l >> 4;        // quad group 0..3
    const int c    = l & 15;        // col (query) index within 16
    const int h    = kvh*2 + (w >> 2);
    const int wq   = w & 3;         // query group within head

    __shared__ short Ks[64 * 128];   // 16 KB DMA image (swizzled rows)
    __shared__ short Vts[128 * 64];  // 16 KB DMA image -> 32 KB total

    // ---- Q fragments in registers: bq[kk] = Q[wq*16+c][kk*32+q4*8 ..+8] ----
    short8 bq[4];
    {
        const u16* qrow = qkv + (size_t)(t0 + wq*16 + c) * QKV_N + h*HD;
        #pragma unroll
        for (int kk = 0; kk < 4; ++kk)
            bq[kk] = *(const short8*)(qrow + kk*32 + q4*8);
    }

    float m_run = -3.0e38f, l_run = 0.f;
    floatx4 accO[8];
    #pragma unroll
    for (int db = 0; db < 8; ++db) accO[db] = (floatx4){0.f, 0.f, 0.f, 0.f};

    const float Cs = 0.12751744f;   // (1/sqrt(128)) * log2(e)

    const int nt  = qt + 1;
    const int nh0 = (nt + 1) >> 1;          // half0: [0,nh0), half1: [nh0,nt)
    const int tlo = half ? nh0 : 0;
    const int thi = half ? nt  : nh0;

    for (int tile = tlo; tile < thi; ++tile) {
        __syncthreads();   // prev iteration's LDS reads complete
        {   // ---- DMA stage: waves 0-3 -> K image, waves 4-7 -> Vt image ----
            const size_t tb = (size_t)(kvh*32 + tile) * 8192;
            const u16* g = (w < 4 ? Kp + tb + w*2048 : Vtp + tb + (w-4)*2048) + l*8;
            short* p = (w < 4) ? (Ks + w*2048) : (Vts + (w-4)*2048);
            #pragma unroll
            for (int i = 0; i < 4; ++i)
                __builtin_amdgcn_global_load_lds(
                    (const __attribute__((address_space(1))) u32*)(g + i*512),
                    (__attribute__((address_space(3))) u32*)(p + i*512), 16, 0, 0);
        }
        __syncthreads();

        // ---- S^T = K Q^T : accS[sb] = s rows [16sb,16sb+16), q col wq*16+c
        // ak phys: row*128 + ((kk*4+q4)^c)*8   (row&15 == c)
        floatx4 accS[4];
        #pragma unroll
        for (int sb = 0; sb < 4; ++sb) accS[sb] = (floatx4){0.f, 0.f, 0.f, 0.f};
        #pragma unroll
        for (int kk = 0; kk < 4; ++kk) {
            #pragma unroll
            for (int sb = 0; sb < 4; ++sb) {
                short8 ak = *(const short8*)(Ks + (sb*16 + c)*128 + ((kk*4 + q4) ^ c)*8);
                accS[sb] = __builtin_amdgcn_mfma_f32_16x16x32_bf16(ak, bq[kk], accS[sb], 0, 0, 0);
            }
        }

        // ---- causal mask on the diagonal tile ----
        if (tile == qt) {
            #pragma unroll
            for (int sb = 0; sb < 4; ++sb)
                #pragma unroll
                for (int r = 0; r < 4; ++r) {
                    const int s_loc = sb*16 + q4*4 + r;
                    const int t_loc = wq*16 + c;
                    if (s_loc > t_loc) accS[sb][r] = -1.0e30f;
                }
        }

        // ---- online softmax (per query col c) ----
        float mt = -3.0e38f;
        #pragma unroll
        for (int sb = 0; sb < 4; ++sb)
            #pragma unroll
            for (int r = 0; r < 4; ++r) mt = fmaxf(mt, accS[sb][r]);
        mt = fmaxf(mt, __shfl_xor(mt, 16));
        mt = fmaxf(mt, __shfl_xor(mt, 32));

        const float m_new = fmaxf(m_run, mt);
        const float alpha = exp2f((m_run - m_new) * Cs);  // 0 on first tile
        m_run = m_new;

        float P[4][4];
        float lsum = 0.f;
        #pragma unroll
        for (int sb = 0; sb < 4; ++sb)
            #pragma unroll
            for (int r = 0; r < 4; ++r) {
                const float e = exp2f((accS[sb][r] - m_new) * Cs);
                P[sb][r] = e;
                lsum += e;
            }
        lsum += __shfl_xor(lsum, 16);
        lsum += __shfl_xor(lsum, 32);
        l_run = l_run * alpha + lsum;

        // ---- rescale O by alpha (alpha per col c; O rows are 4q+r) ----
        #pragma unroll
        for (int r = 0; r < 4; ++r) {
            const float ar = __shfl(alpha, (l & 48) | (q4*4 + r));
            #pragma unroll
            for (int db = 0; db < 8; ++db) accO[db][r] *= ar;
        }

        // ---- pack P to bf16 pairs ----
        u32 Pp[4][2];
        #pragma unroll
        for (int sb = 0; sb < 4; ++sb)
            #pragma unroll
            for (int p = 0; p < 2; ++p)
                Pp[sb][p] = (u32)f2bf(P[sb][2*p]) | ((u32)f2bf(P[sb][2*p+1]) << 16);

        // ---- PV: O[m][d] += P[m][s] * Vt[d][s] ----
        // bv phys: d'*64 + ((k2*4+q4)^(c&7))*8   (d' = db*16+c)
        const int src0 = ((2*q4    ) & 3) * 16 + c;
        const int src1 = ((2*q4 + 1) & 3) * 16 + c;
        const bool hiq = q4 >= 2;
        #pragma unroll
        for (int k2 = 0; k2 < 2; ++k2) {
            u32 x0 = __shfl(Pp[2*k2][0],   src0), y0 = __shfl(Pp[2*k2+1][0], src0);
            u32 x1 = __shfl(Pp[2*k2][1],   src0), y1 = __shfl(Pp[2*k2+1][1], src0);
            u32 x2 = __shfl(Pp[2*k2][0],   src1), y2 = __shfl(Pp[2*k2+1][0], src1);
            u32 x3 = __shfl(Pp[2*k2][1],   src1), y3 = __shfl(Pp[2*k2+1][1], src1);
            u32x4 av;
            av.x = hiq ? y0 : x0;  av.y = hiq ? y1 : x1;
            av.z = hiq ? y2 : x2;  av.w = hiq ? y3 : x3;
            const short8 aP = __builtin_bit_cast(short8, av);
            #pragma unroll
            for (int db = 0; db < 8; ++db) {
                short8 bv = *(const short8*)(Vts + (db*16 + c)*64 + (((k2*4 + q4) ^ (c & 7)))*8);
                accO[db] = __builtin_amdgcn_mfma_f32_16x16x32_bf16(aP, bv, accO[db], 0, 0, 0);
            }
        }
    }

    // ---- write UNNORMALIZED partial + (m,l) per query row ----
    const size_t pbase = (size_t)(half * NH + h) * T_TOK;
    #pragma unroll
    for (int r = 0; r < 4; ++r) {
        const int qloc = q4*4 + r;
        const float mr = __shfl(m_run, (l & 48) | qloc);
        const float lr = __shfl(l_run, (l & 48) | qloc);
        const int row_g = t0 + wq*16 + qloc;
        u16* op = Opart + (pbase + row_g) * HD;
        #pragma unroll
        for (int db = 0; db < 8; ++db)
            op[db*16 + c] = f2bf(accO[db][r]);
        if (c == 0) ml[pbase + row_g] = make_float2(mr, lr);
    }
}

// ---------------------------------------------------------------------------
// Merge the two split-s partials -> q slot of qkv (bf16).
// ---------------------------------------------------------------------------
__global__ __launch_bounds__(256) void attn_combine(
    const u16* __restrict__ Opart, const float2* __restrict__ ml,
    u16* __restrict__ qkv)
{
    const int idx = blockIdx.x * 256 + threadIdx.x;
    const int d = idx & (HD - 1);
    const int t = (idx >> 7) & (T_TOK - 1);
    const int h = idx >> 18;
    const size_t iA = (size_t)h * T_TOK + t;
    const size_t iB = (size_t)(NH + h) * T_TOK + t;
    const float2 a = ml[iA];
    const float2 b = ml[iB];
    const float Cs = 0.12751744f;
    const float mM = fmaxf(a.x, b.x);
    const float wA = exp2f((a.x - mM) * Cs);
    const float wB = exp2f((b.x - mM) * Cs);
    const float OA = bf2f(Opart[iA * HD + d]);
    const float OB = bf2f(Opart[iB * HD + d]);
    const float o = (wA * OA + wB * OB) / (wA * a.y + wB * b.y);
    qkv[(size_t)t * QKV_N + h * HD + d] = f2bf(o);
}

// ---------------------------------------------------------------------------
extern "C" void kernel_launch(void* const* d_in, const int* in_sizes, int n_in,
                              void* d_out, int out_size, void* d_ws, size_t ws_size,
                              hipStream_t stream)
{
    const float* hidden    = (const float*)d_in[0];   // T x HID
    const int*   positions = (const int*)  d_in[1];   // T
    const float* qkv_w     = (const float*)d_in[2];   // 4096 x 2048
    const float* o_w       = (const float*)d_in[3];   // 2048 x 2048
    const float* q_norm_w  = (const float*)d_in[4];   // 128
    const float* k_norm_w  = (const float*)d_in[5];   // 128
    float* out = (float*)d_out;                       // T x HID (f32)

    // ws: [qkvbf 16MB][wbf 16MB][abf 8MB][Kp 4MB][Vtp 4MB] = 48 MB
    // wbf -> Opart during attn; abf -> hidden bf16, then ml, then o_w bf16.
    u16* qkvbf = (u16*)d_ws;
    u16* wbf   = qkvbf + (size_t)T_TOK * QKV_N;
    u16* abf   = wbf   + (size_t)QKV_N * HID;
    u16* kpb   = abf   + (size_t)T_TOK * HID;
    u16* vpb   = kpb   + (size_t)NKV * T_TOK * HD;

    cvt_f32_bf16<<<(T_TOK*HID)/2048, 256, 0, stream>>>(hidden, abf);
    cvt_f32_bf16<<<(QKV_N*HID)/2048, 256, 0, stream>>>(qkv_w, wbf);

    // 1) qkv(bf16) = hidden @ qkv_w^T
    gemm_bt_bf16<true><<<dim3(QKV_N/128, T_TOK/128), 256, 0, stream>>>(
        abf, wbf, qkvbf, HID, HID, HID, QKV_N);

    // 2) rmsnorm + rope on q,k
    norm_rope<<<dim3(T_TOK, NH + NKV), 128, 0, stream>>>(
        qkvbf, positions, q_norm_w, k_norm_w);

    // 2b) pack K and V^T into tile-contiguous swizzled DMA images
    k_pack<<<dim3(T_TOK/64, NKV), 256, 0, stream>>>(qkvbf, kpb);
    v_pack<<<dim3(T_TOK/64, NKV), 256, 0, stream>>>(qkvbf, vpb);

    // 3) head-pair-merged split-s MFMA flash attention -> partials
    attn_mfma<<<512, 512, 0, stream>>>(qkvbf, kpb, vpb, wbf, (float2*)abf);

    // 3b) combine partials -> q slots of qkv
    attn_combine<<<(NH*T_TOK*HD)/256, 256, 0, stream>>>(
        wbf, (const float2*)abf, qkvbf);

    // 4) out(f32) = o @ o_w^T  (o_w bf16 into abf, dead after combine)
    cvt_f32_bf16<<<(HID*HID)/2048, 256, 0, stream>>>(o_w, abf);
    gemm_bt_bf16<false><<<dim3(HID/128, T_TOK/128), 256, 0, stream>>>(
        qkvbf, abf, out, HID, QKV_N, HID, HID);
}

// Round 10
// 285.536 us; speedup vs baseline: 1.2108x; 1.0210x over previous
//
#include <hip/hip_runtime.h>
#include <math.h>

// Qwen3Attention: T=2048, HID=2048, H=16, KV=8, D=128
#define T_TOK 2048
#define HID 2048
#define NH 16
#define NKV 8
#define HD 128
#define QKV_N 4096
#define EPS 1e-6f

typedef unsigned short u16;
typedef unsigned int   u32;
typedef __attribute__((ext_vector_type(8))) u16   u16x8;
typedef __attribute__((ext_vector_type(8))) short short8;
typedef __attribute__((ext_vector_type(4))) float floatx4;
typedef __attribute__((ext_vector_type(4))) u32   u32x4;

__device__ __forceinline__ u16 f2bf(float x) {           // RNE f32->bf16
    u32 u = __float_as_uint(x);
    u = (u + 0x7fffu + ((u >> 16) & 1u)) >> 16;
    return (u16)u;
}
__device__ __forceinline__ float bf2f(u16 h) {
    return __uint_as_float(((u32)h) << 16);
}

// ---------------------------------------------------------------------------
// f32 -> bf16 elementwise (8 elems/thread). n must be a multiple of 2048.
// ---------------------------------------------------------------------------
__global__ __launch_bounds__(256) void cvt_f32_bf16(
    const float* __restrict__ in, u16* __restrict__ out)
{
    const size_t i = ((size_t)blockIdx.x * 256 + threadIdx.x) * 8;
    float4 a = *(const float4*)(in + i);
    float4 b = *(const float4*)(in + i + 4);
    u16x8 o;
    o[0] = f2bf(a.x); o[1] = f2bf(a.y); o[2] = f2bf(a.z); o[3] = f2bf(a.w);
    o[4] = f2bf(b.x); o[5] = f2bf(b.y); o[6] = f2bf(b.z); o[7] = f2bf(b.w);
    *(u16x8*)(out + i) = o;
}

// ---------------------------------------------------------------------------
// bf16 MFMA GEMM (m97 pattern): C[M,N] = A[M,K]*B[N,K]^T
// 128x128 tile, BK=32, 256 thr; global_load_lds width=16 staging.
// ---------------------------------------------------------------------------
template<bool OUT_BF16>
__global__ __launch_bounds__(256) void gemm_bt_bf16(
    const u16* __restrict__ A, const u16* __restrict__ B,
    void* __restrict__ Cv, int K, int lda, int ldb, int ldc)
{
    __shared__ short As[128 * 32];
    __shared__ short Bs[128 * 32];

    const int tid = threadIdx.x;
    const int w   = tid >> 6;
    const int l   = tid & 63;
    const int m0  = blockIdx.y * 128;
    const int n0  = blockIdx.x * 128;
    const int wm  = (w >> 1) * 64;
    const int wn  = (w & 1) * 64;
    const int lm  = l & 15;
    const int ko8 = (l >> 4) * 8;

    const u16* gA0 = A + (size_t)(m0      + (tid >> 2)) * lda + (tid & 3) * 8;
    const u16* gA1 = A + (size_t)(m0 + 64 + (tid >> 2)) * lda + (tid & 3) * 8;
    const u16* gB0 = B + (size_t)(n0      + (tid >> 2)) * ldb + (tid & 3) * 8;
    const u16* gB1 = B + (size_t)(n0 + 64 + (tid >> 2)) * ldb + (tid & 3) * 8;
    short* lA0 = As + w * 512;
    short* lA1 = As + 2048 + w * 512;
    short* lB0 = Bs + w * 512;
    short* lB1 = Bs + 2048 + w * 512;

    floatx4 acc[4][4];
    #pragma unroll
    for (int i = 0; i < 4; ++i)
        #pragma unroll
        for (int j = 0; j < 4; ++j) acc[i][j] = (floatx4){0.f, 0.f, 0.f, 0.f};

    for (int k0 = 0; k0 < K; k0 += 32) {
        __syncthreads();
        __builtin_amdgcn_global_load_lds(
            (const __attribute__((address_space(1))) u32*)(gA0 + k0),
            (__attribute__((address_space(3))) u32*)lA0, 16, 0, 0);
        __builtin_amdgcn_global_load_lds(
            (const __attribute__((address_space(1))) u32*)(gA1 + k0),
            (__attribute__((address_space(3))) u32*)lA1, 16, 0, 0);
        __builtin_amdgcn_global_load_lds(
            (const __attribute__((address_space(1))) u32*)(gB0 + k0),
            (__attribute__((address_space(3))) u32*)lB0, 16, 0, 0);
        __builtin_amdgcn_global_load_lds(
            (const __attribute__((address_space(1))) u32*)(gB1 + k0),
            (__attribute__((address_space(3))) u32*)lB1, 16, 0, 0);
        __syncthreads();

        short8 af[4], bfr[4];
        #pragma unroll
        for (int i = 0; i < 4; ++i)
            af[i] = *(const short8*)(As + (wm + i * 16 + lm) * 32 + ko8);
        #pragma unroll
        for (int j = 0; j < 4; ++j)
            bfr[j] = *(const short8*)(Bs + (wn + j * 16 + lm) * 32 + ko8);
        #pragma unroll
        for (int i = 0; i < 4; ++i)
            #pragma unroll
            for (int j = 0; j < 4; ++j)
                acc[i][j] = __builtin_amdgcn_mfma_f32_16x16x32_bf16(
                    af[i], bfr[j], acc[i][j], 0, 0, 0);
    }

    const int r0 = (l >> 4) * 4;
    #pragma unroll
    for (int i = 0; i < 4; ++i)
        #pragma unroll
        for (int j = 0; j < 4; ++j)
            #pragma unroll
            for (int r = 0; r < 4; ++r) {
                const int row = m0 + wm + i * 16 + r0 + r;
                const int col = n0 + wn + j * 16 + lm;
                if (OUT_BF16)
                    ((u16*)Cv)[(size_t)row * ldc + col] = f2bf(acc[i][j][r]);
                else
                    ((float*)Cv)[(size_t)row * ldc + col] = acc[i][j][r];
            }
}

// ---------------------------------------------------------------------------
// Fused prep: RMSNorm+RoPE for q heads {2kvh, 2kvh+1} and k head kvh
// (wave-per-row, shfl-based), K written directly into the packed swizzled
// DMA image, plus V transpose+pack. grid=(T/64, NKV), 256 thr = 4 waves.
// Replaces norm_rope + k_pack + v_pack.
// Row scheme: lane l holds elems {2l, 2l+1}; RMS sum via shfl_xor 1..32;
// RoPE partner (d +/- 64) lives at lane l^32; angle depends only on (t, i)
// so trig is computed once per row and reused for all 3 heads.
// ---------------------------------------------------------------------------
__global__ __launch_bounds__(256) void prep(
    u16* __restrict__ qkv, const int* __restrict__ positions,
    const float* __restrict__ qw, const float* __restrict__ kw,
    u16* __restrict__ Kp, u16* __restrict__ Vtp)
{
    const int tile = blockIdx.x, kvh = blockIdx.y;
    const int tid = threadIdx.x;
    const int w = tid >> 6, l = tid & 63;
    const int t0 = tile * 64;

    const float qw0 = qw[2*l], qw1 = qw[2*l+1];
    const float kw0 = kw[2*l], kw1 = kw[2*l+1];
    const int   i0  = (2*l) & 63;            // rotary index (even)
    const float if0 = exp2f(-(float)i0     * 0.311430758895690f); // log2(1e6)/64
    const float if1 = exp2f(-(float)(i0+1) * 0.311430758895690f);

    for (int rr = w; rr < 64; rr += 4) {
        const int t = t0 + rr;
        const int pos = positions[t];
        const float a0 = (float)pos * if0;
        const float a1 = (float)pos * if1;
        const float s0 = sinf(a0), c0 = cosf(a0);   // NOTE: not sincosf (r2 trap)
        const float s1 = sinf(a1), c1 = cosf(a1);

        #pragma unroll
        for (int pass = 0; pass < 3; ++pass) {
            const int off = (pass < 2) ? (2*kvh + pass)*HD : NH*HD + kvh*HD;
            const float w0 = (pass < 2) ? qw0 : kw0;
            const float w1 = (pass < 2) ? qw1 : kw1;
            u16* p = qkv + (size_t)t*QKV_N + off;

            const u32 pk = *(const u32*)(p + 2*l);
            const float x0 = bf2f((u16)pk), x1 = bf2f((u16)(pk >> 16));
            float ss = x0*x0 + x1*x1;
            #pragma unroll
            for (int x = 1; x < 64; x <<= 1) ss += __shfl_xor(ss, x);
            const float rs = rsqrtf(ss * (1.0f/128.0f) + EPS);
            const float xn0 = x0 * rs * w0, xn1 = x1 * rs * w1;
            const float px0 = __shfl_xor(xn0, 32);
            const float px1 = __shfl_xor(xn1, 32);

            float o0, o1;
            if (l < 32) { o0 = xn0*c0 - px0*s0; o1 = xn1*c1 - px1*s1; }
            else        { o0 = xn0*c0 + px0*s0; o1 = xn1*c1 + px1*s1; }
            const u32 outpk = (u32)f2bf(o0) | ((u32)f2bf(o1) << 16);

            if (pass < 2) {
                *(u32*)(p + 2*l) = outpk;    // q: back in place
            } else {
                // K -> packed swizzled image: chunk ch=l>>2 at phys ch^(rr&15)
                const int ch = l >> 2;
                u16* dst = Kp + ((size_t)(kvh*32 + tile)*64 + rr)*128
                              + (ch ^ (rr & 15))*8 + (l & 3)*2;
                *(u32*)dst = outpk;
            }
        }
    }

    // ---- V transpose + swizzled pack (as old v_pack) ----
    __shared__ u16 tl[64][136];
    {
        const int t  = tid >> 2;
        const int c0 = (tid & 3) * 32;
        const u16* src = qkv + (size_t)(t0 + t)*QKV_N + NH*HD + NKV*HD + kvh*HD + c0;
        #pragma unroll
        for (int p2 = 0; p2 < 4; ++p2)
            *(u16x8*)(&tl[t][c0 + p2*8]) = *(const u16x8*)(src + p2*8);
    }
    __syncthreads();
    {
        u16* dstb = Vtp + (size_t)(kvh*32 + tile) * 128 * 64;
        #pragma unroll
        for (int i = 0; i < 4; ++i) {
            const int id = tid*4 + i;      // over (d,o): 128*8 chunks
            const int d = id >> 3;
            const int o = id & 7;
            const int sb = (o ^ (d & 7)) * 8;
            u16x8 v;
            #pragma unroll
            for (int j = 0; j < 8; ++j) v[j] = tl[sb + j][d];
            *(u16x8*)(dstb + d*64 + o*8) = v;
        }
    }
}

// ---------------------------------------------------------------------------
// Head-pair-merged split-s MFMA flash attention, DOUBLE-BUFFERED DMA.
// grid = 512 blocks x 512 thr (8 waves), 2 blocks/CU. Decode as r8.
// Per iter: barrier (drains DMA for buf[cur]) -> issue DMA for tile+1 into
// buf[cur^1] -> compute on buf[cur]. The next-tile DMA has the whole
// S/softmax/PV phase to land, so the barrier drain is ~free.
// ---------------------------------------------------------------------------
__global__ __launch_bounds__(512) void attn_mfma(
    const u16* __restrict__ qkv, const u16* __restrict__ Kp,
    const u16* __restrict__ Vtp,
    u16* __restrict__ Opart, float2* __restrict__ ml)
{
    const int id   = blockIdx.x;
    const int half = id >> 8;
    const int kvh  = id & 7;
    const int bid  = (id & 255) >> 3;              // 0..31
    const int qt   = half ? bid : 31 - bid;
    const int t0   = qt * 64;
    const int tid  = threadIdx.x;
    const int w    = tid >> 6;      // 0..7
    const int l    = tid & 63;
    const int q4   = l >> 4;        // quad group 0..3
    const int c    = l & 15;        // col (query) index within 16
    const int h    = kvh*2 + (w >> 2);
    const int wq   = w & 3;         // query group within head

    __shared__ short Ks[2][64 * 128];   // 2 x 16 KB
    __shared__ short Vts[2][128 * 64];  // 2 x 16 KB -> 64 KB total

    // ---- Q fragments in registers ----
    short8 bq[4];
    {
        const u16* qrow = qkv + (size_t)(t0 + wq*16 + c) * QKV_N + h*HD;
        #pragma unroll
        for (int kk = 0; kk < 4; ++kk)
            bq[kk] = *(const short8*)(qrow + kk*32 + q4*8);
    }

    float m_run = -3.0e38f, l_run = 0.f;
    floatx4 accO[8];
    #pragma unroll
    for (int db = 0; db < 8; ++db) accO[db] = (floatx4){0.f, 0.f, 0.f, 0.f};

    const float Cs = 0.12751744f;   // (1/sqrt(128)) * log2(e)

    const int nt  = qt + 1;
    const int nh0 = (nt + 1) >> 1;          // half0: [0,nh0), half1: [nh0,nt)
    const int tlo = half ? nh0 : 0;
    const int thi = half ? nt  : nh0;

    // DMA issue: waves 0-3 stage the K image, waves 4-7 the Vt image.
    auto issue = [&](int tile, int buf) {
        const size_t tb = (size_t)(kvh*32 + tile) * 8192;
        const u16* g = (w < 4 ? Kp + tb + w*2048 : Vtp + tb + (w-4)*2048) + l*8;
        short* p = (w < 4) ? (Ks[buf] + w*2048) : (Vts[buf] + (w-4)*2048);
        #pragma unroll
        for (int i = 0; i < 4; ++i)
            __builtin_amdgcn_global_load_lds(
                (const __attribute__((address_space(1))) u32*)(g + i*512),
                (__attribute__((address_space(3))) u32*)(p + i*512), 16, 0, 0);
    };

    if (tlo < thi) issue(tlo, 0);
    int cur = 0;

    for (int tile = tlo; tile < thi; ++tile) {
        __syncthreads();   // drains buf[cur] DMA; orders vs prev compute
        if (tile + 1 < thi) issue(tile + 1, cur ^ 1);

        const short* Kc = Ks[cur];
        const short* Vc = Vts[cur];

        // ---- S^T = K Q^T ----  ak phys: row*128 + ((kk*4+q4)^c)*8
        floatx4 accS[4];
        #pragma unroll
        for (int sb = 0; sb < 4; ++sb) accS[sb] = (floatx4){0.f, 0.f, 0.f, 0.f};
        #pragma unroll
        for (int kk = 0; kk < 4; ++kk) {
            #pragma unroll
            for (int sb = 0; sb < 4; ++sb) {
                short8 ak = *(const short8*)(Kc + (sb*16 + c)*128 + ((kk*4 + q4) ^ c)*8);
                accS[sb] = __builtin_amdgcn_mfma_f32_16x16x32_bf16(ak, bq[kk], accS[sb], 0, 0, 0);
            }
        }

        // ---- causal mask on the diagonal tile ----
        if (tile == qt) {
            #pragma unroll
            for (int sb = 0; sb < 4; ++sb)
                #pragma unroll
                for (int r = 0; r < 4; ++r) {
                    const int s_loc = sb*16 + q4*4 + r;
                    const int t_loc = wq*16 + c;
                    if (s_loc > t_loc) accS[sb][r] = -1.0e30f;
                }
        }

        // ---- online softmax (per query col c) ----
        float mt = -3.0e38f;
        #pragma unroll
        for (int sb = 0; sb < 4; ++sb)
            #pragma unroll
            for (int r = 0; r < 4; ++r) mt = fmaxf(mt, accS[sb][r]);
        mt = fmaxf(mt, __shfl_xor(mt, 16));
        mt = fmaxf(mt, __shfl_xor(mt, 32));

        const float m_new = fmaxf(m_run, mt);
        const float alpha = exp2f((m_run - m_new) * Cs);  // 0 on first tile
        m_run = m_new;

        float P[4][4];
        float lsum = 0.f;
        #pragma unroll
        for (int sb = 0; sb < 4; ++sb)
            #pragma unroll
            for (int r = 0; r < 4; ++r) {
                const float e = exp2f((accS[sb][r] - m_new) * Cs);
                P[sb][r] = e;
                lsum += e;
            }
        lsum += __shfl_xor(lsum, 16);
        lsum += __shfl_xor(lsum, 32);
        l_run = l_run * alpha + lsum;

        // ---- rescale O by alpha (alpha per col c; O rows are 4q+r) ----
        #pragma unroll
        for (int r = 0; r < 4; ++r) {
            const float ar = __shfl(alpha, (l & 48) | (q4*4 + r));
            #pragma unroll
            for (int db = 0; db < 8; ++db) accO[db][r] *= ar;
        }

        // ---- pack P to bf16 pairs ----
        u32 Pp[4][2];
        #pragma unroll
        for (int sb = 0; sb < 4; ++sb)
            #pragma unroll
            for (int p = 0; p < 2; ++p)
                Pp[sb][p] = (u32)f2bf(P[sb][2*p]) | ((u32)f2bf(P[sb][2*p+1]) << 16);

        // ---- PV: O[m][d] += P[m][s] * Vt[d][s] ----
        const int src0 = ((2*q4    ) & 3) * 16 + c;
        const int src1 = ((2*q4 + 1) & 3) * 16 + c;
        const bool hiq = q4 >= 2;
        #pragma unroll
        for (int k2 = 0; k2 < 2; ++k2) {
            u32 x0 = __shfl(Pp[2*k2][0],   src0), y0 = __shfl(Pp[2*k2+1][0], src0);
            u32 x1 = __shfl(Pp[2*k2][1],   src0), y1 = __shfl(Pp[2*k2+1][1], src0);
            u32 x2 = __shfl(Pp[2*k2][0],   src1), y2 = __shfl(Pp[2*k2+1][0], src1);
            u32 x3 = __shfl(Pp[2*k2][1],   src1), y3 = __shfl(Pp[2*k2+1][1], src1);
            u32x4 av;
            av.x = hiq ? y0 : x0;  av.y = hiq ? y1 : x1;
            av.z = hiq ? y2 : x2;  av.w = hiq ? y3 : x3;
            const short8 aP = __builtin_bit_cast(short8, av);
            #pragma unroll
            for (int db = 0; db < 8; ++db) {
                short8 bv = *(const short8*)(Vc + (db*16 + c)*64 + (((k2*4 + q4) ^ (c & 7)))*8);
                accO[db] = __builtin_amdgcn_mfma_f32_16x16x32_bf16(aP, bv, accO[db], 0, 0, 0);
            }
        }
        cur ^= 1;
    }

    // ---- write UNNORMALIZED partial + (m,l) per query row ----
    const size_t pbase = (size_t)(half * NH + h) * T_TOK;
    #pragma unroll
    for (int r = 0; r < 4; ++r) {
        const int qloc = q4*4 + r;
        const float mr = __shfl(m_run, (l & 48) | qloc);
        const float lr = __shfl(l_run, (l & 48) | qloc);
        const int row_g = t0 + wq*16 + qloc;
        u16* op = Opart + (pbase + row_g) * HD;
        #pragma unroll
        for (int db = 0; db < 8; ++db)
            op[db*16 + c] = f2bf(accO[db][r]);
        if (c == 0) ml[pbase + row_g] = make_float2(mr, lr);
    }
}

// ---------------------------------------------------------------------------
// Merge the two split-s partials -> q slot of qkv (bf16). 8 elems/thread.
// idx over NH*T*16 chunk-units.
// ---------------------------------------------------------------------------
__global__ __launch_bounds__(256) void attn_combine(
    const u16* __restrict__ Opart, const float2* __restrict__ ml,
    u16* __restrict__ qkv)
{
    const int idx = blockIdx.x * 256 + threadIdx.x;
    const int c16 = idx & 15;                 // 16 chunks of 8 per row
    const int t   = (idx >> 4) & (T_TOK - 1);
    const int h   = idx >> 15;
    const size_t iA = (size_t)h * T_TOK + t;
    const size_t iB = (size_t)(NH + h) * T_TOK + t;
    const float2 a = ml[iA];
    const float2 b = ml[iB];
    const float Cs = 0.12751744f;
    const float mM = fmaxf(a.x, b.x);
    const float wA = exp2f((a.x - mM) * Cs);
    const float wB = exp2f((b.x - mM) * Cs);
    const float inv = 1.0f / (wA * a.y + wB * b.y);
    const u16x8 A = *(const u16x8*)(Opart + iA * HD + c16*8);
    const u16x8 B = *(const u16x8*)(Opart + iB * HD + c16*8);
    u16x8 o;
    #pragma unroll
    for (int j = 0; j < 8; ++j)
        o[j] = f2bf((wA * bf2f(A[j]) + wB * bf2f(B[j])) * inv);
    *(u16x8*)(qkv + (size_t)t * QKV_N + h * HD + c16*8) = o;
}

// ---------------------------------------------------------------------------
extern "C" void kernel_launch(void* const* d_in, const int* in_sizes, int n_in,
                              void* d_out, int out_size, void* d_ws, size_t ws_size,
                              hipStream_t stream)
{
    const float* hidden    = (const float*)d_in[0];   // T x HID
    const int*   positions = (const int*)  d_in[1];   // T
    const float* qkv_w     = (const float*)d_in[2];   // 4096 x 2048
    const float* o_w       = (const float*)d_in[3];   // 2048 x 2048
    const float* q_norm_w  = (const float*)d_in[4];   // 128
    const float* k_norm_w  = (const float*)d_in[5];   // 128
    float* out = (float*)d_out;                       // T x HID (f32)

    // ws: [qkvbf 16MB][wbf 16MB][abf 8MB][Kp 4MB][Vtp 4MB] = 48 MB
    // wbf -> Opart during attn; abf -> hidden bf16, then ml, then o_w bf16.
    u16* qkvbf = (u16*)d_ws;
    u16* wbf   = qkvbf + (size_t)T_TOK * QKV_N;
    u16* abf   = wbf   + (size_t)QKV_N * HID;
    u16* kpb   = abf   + (size_t)T_TOK * HID;
    u16* vpb   = kpb   + (size_t)NKV * T_TOK * HD;

    cvt_f32_bf16<<<(T_TOK*HID)/2048, 256, 0, stream>>>(hidden, abf);
    cvt_f32_bf16<<<(QKV_N*HID)/2048, 256, 0, stream>>>(qkv_w, wbf);

    // 1) qkv(bf16) = hidden @ qkv_w^T
    gemm_bt_bf16<true><<<dim3(QKV_N/128, T_TOK/128), 256, 0, stream>>>(
        abf, wbf, qkvbf, HID, HID, HID, QKV_N);

    // 2) fused rmsnorm+rope (q in place, K packed) + V transpose-pack
    prep<<<dim3(T_TOK/64, NKV), 256, 0, stream>>>(
        qkvbf, positions, q_norm_w, k_norm_w, kpb, vpb);

    // 3) head-pair-merged split-s MFMA flash attention (double-buffered DMA)
    attn_mfma<<<512, 512, 0, stream>>>(qkvbf, kpb, vpb, wbf, (float2*)abf);

    // 3b) combine partials -> q slots of qkv
    attn_combine<<<(NH*T_TOK*16)/256, 256, 0, stream>>>(
        wbf, (const float2*)abf, qkvbf);

    // 4) out(f32) = o @ o_w^T  (o_w bf16 into abf, dead after combine)
    cvt_f32_bf16<<<(HID*HID)/2048, 256, 0, stream>>>(o_w, abf);
    gemm_bt_bf16<false><<<dim3(HID/128, T_TOK/128), 256, 0, stream>>>(
        qkvbf, abf, out, HID, QKV_N, HID, HID);
}